// Round 8
// baseline (43.321 us; speedup 1.0000x reference)
//
#include <hip/hip_runtime.h>

#define NPOS 1024
#define OUTLEN 2048
#define PAD_SYM 4
#define WAVES_PER_BLOCK 2
#define ROWB 2176   // 2048 row bytes + 64 dump slots + pad

typedef int iv4 __attribute__((ext_vector_type(4)));

__global__ __launch_bounds__(128) void ids_gallager_kernel(
    const int* __restrict__ x, const int* __restrict__ mask,
    const int* __restrict__ ins_rand, const int* __restrict__ sub_off,
    int* __restrict__ out, int B)
{
    __shared__ alignas(16) unsigned char lds[WAVES_PER_BLOCK][ROWB];

    const int wave = (int)(blockIdx.x * WAVES_PER_BLOCK + (threadIdx.x >> 6));
    const int w    = (int)(threadIdx.x >> 6);
    const int lane = (int)(threadIdx.x & 63);
    if (wave >= B) return;

    const int4* mv  = (const int4*)(mask     + (size_t)wave * NPOS);   // 256 int4
    const int4* xv  = (const int4*)(x        + (size_t)wave * NPOS);
    const int4* ivv = (const int4*)(ins_rand + (size_t)wave * OUTLEN); // 512 int4
    const int4* svv = (const int4*)(sub_off  + (size_t)wave * OUTLEN);
    int* outr = out + (size_t)wave * OUTLEN;

    unsigned char* row   = lds[w];
    int*           row32 = (int*)row;
    const int dump = OUTLEN + lane;

    // ---- issue ALL global loads upfront: one latency exposure ----
    int4 m4[4], x4[4], ia[4], ib[4], sa[4], sb[4];
#pragma unroll
    for (int c = 0; c < 4; ++c) {
        m4[c] = mv[c * 64 + lane];           // stride 16B, coalesced
        x4[c] = xv[c * 64 + lane];
        ia[c] = ivv[c * 128 + 2 * lane];     // stride 32B
        ib[c] = ivv[c * 128 + 2 * lane + 1];
        sa[c] = svv[c * 128 + 2 * lane];
        sb[c] = svv[c * 128 + 2 * lane + 1];
    }

    // ---- per-chunk emit counts (lane owns positions 4l..4l+3 of each chunk) ----
    int cnt[4];
#pragma unroll
    for (int c = 0; c < 4; ++c) {
        const int mm[4] = { m4[c].x, m4[c].y, m4[c].z, m4[c].w };
        int s = 0;
#pragma unroll
        for (int k = 0; k < 4; ++k)
            s += (mm[k] == 0) ? 2 : ((mm[k] == 1) ? 0 : 1);
        cnt[c] = s;
    }

    // ---- SWAR scan: two u32s, 16-bit fields, two independent 6-step chains ----
    unsigned pA = (unsigned)cnt[0] | ((unsigned)cnt[1] << 16);
    unsigned pB = (unsigned)cnt[2] | ((unsigned)cnt[3] << 16);
#pragma unroll
    for (int d = 1; d < 64; d <<= 1) {
        const unsigned tA = (unsigned)__shfl_up((int)pA, d, 64);
        const unsigned tB = (unsigned)__shfl_up((int)pB, d, 64);
        if (lane >= d) { pA += tA; pB += tB; }
    }
    const unsigned totA = (unsigned)__shfl((int)pA, 63, 64);
    const unsigned totB = (unsigned)__shfl((int)pB, 63, 64);
    const int tot0 = (int)(totA & 0xffffu), tot1 = (int)(totA >> 16);
    const int tot2 = (int)(totB & 0xffffu), tot3 = (int)(totB >> 16);
    const int incl[4] = { (int)(pA & 0xffffu), (int)(pA >> 16),
                          (int)(pB & 0xffffu), (int)(pB >> 16) };
    const int carry[4] = { 0, tot0, tot0 + tot1, tot0 + tot1 + tot2 };
    const int total = carry[3] + tot3;

    // ---- branch-free emit; dead writes to per-lane dump slot ----
#pragma unroll
    for (int c = 0; c < 4; ++c) {
        const int mm[4] = { m4[c].x, m4[c].y, m4[c].z, m4[c].w };
        const int xx[4] = { x4[c].x, x4[c].y, x4[c].z, x4[c].w };
        const int iA[4] = { ia[c].x, ia[c].z, ib[c].x, ib[c].z };
        const int iB[4] = { ia[c].y, ia[c].w, ib[c].y, ib[c].w };
        const int sO[4] = { sa[c].x, sa[c].z, sb[c].x, sb[c].z };

        int p = carry[c] + incl[c] - cnt[c];
#pragma unroll
        for (int k = 0; k < 4; ++k) {
            const int m_  = mm[k];
            const int cc  = (m_ == 0) ? 2 : ((m_ == 1) ? 0 : 1);
            const int sub = (xx[k] + sO[k] + 1) & 3;
            const int e0  = (m_ == 0) ? iA[k] : ((m_ == 2) ? sub : xx[k]);
            row[(cc != 0) ? p       : dump] = (unsigned char)e0;
            row[(cc == 2) ? (p + 1) : dump] = (unsigned char)iB[k];
            p += cc;
        }
    }

    // ---- pad tail bytes [total, OUTLEN) with PAD_SYM ----
    const int a4 = (total + 3) & ~3;
    if (lane < a4 - total) row[total + lane] = (unsigned char)PAD_SYM;
    for (int j4 = (a4 >> 2) + lane; j4 < (OUTLEN >> 2); j4 += 64)
        row32[j4] = 0x04040404;

    // Row buffer is WAVE-private: no cross-wave sync needed. wave_barrier is a
    // compiler-only fence ordering the DS writes above before the DS reads
    // below (same-wave DS ops execute in order on HW; zero runtime cost).
    __builtin_amdgcn_wave_barrier();

    // ---- store: lane reads 1 dword (4 symbols), widens, NT int4 store ----
#pragma unroll
    for (int k = 0; k < 8; ++k) {
        const unsigned int d = *(const unsigned int*)(row + k * 256 + lane * 4);
        iv4 v;
        v.x = (int)(d & 0xffu);
        v.y = (int)((d >> 8)  & 0xffu);
        v.z = (int)((d >> 16) & 0xffu);
        v.w = (int)(d >> 24);
        __builtin_nontemporal_store(v, (iv4*)(outr + k * 256 + lane * 4));
    }
}

extern "C" void kernel_launch(void* const* d_in, const int* in_sizes, int n_in,
                              void* d_out, int out_size, void* d_ws, size_t ws_size,
                              hipStream_t stream) {
    const int* x        = (const int*)d_in[0];
    const int* mask     = (const int*)d_in[1];
    const int* ins_rand = (const int*)d_in[2];
    const int* sub_off  = (const int*)d_in[3];
    int* out            = (int*)d_out;

    const int B = in_sizes[1] / NPOS;           // mask is [B, N]
    const int blocks = (B + WAVES_PER_BLOCK - 1) / WAVES_PER_BLOCK;
    ids_gallager_kernel<<<blocks, 128, 0, stream>>>(x, mask, ins_rand, sub_off, out, B);
}

// Round 9
// 42.398 us; speedup vs baseline: 1.0218x; 1.0218x over previous
//
#include <hip/hip_runtime.h>

#define NPOS 1024
#define OUTLEN 2048
#define PAD_SYM 4
#define ROWB (OUTLEN + 256)   // 2048 row bytes + 256 per-thread dump slots

typedef int iv4 __attribute__((ext_vector_type(4)));

__global__ __launch_bounds__(256) void ids_gallager_kernel(
    const int* __restrict__ x, const int* __restrict__ mask,
    const int* __restrict__ ins_rand, const int* __restrict__ sub_off,
    int* __restrict__ out, int B)
{
    __shared__ alignas(16) unsigned char row[ROWB];
    __shared__ int wtot[4];

    const int rowi = (int)blockIdx.x;          // one row per block
    if (rowi >= B) return;
    const int tid  = (int)threadIdx.x;          // 0..255, owns positions 4t..4t+3
    const int lane = tid & 63;
    const int w    = tid >> 6;

    const int4* mv  = (const int4*)(mask     + (size_t)rowi * NPOS);   // 256 int4
    const int4* xv  = (const int4*)(x        + (size_t)rowi * NPOS);
    const int4* ivv = (const int4*)(ins_rand + (size_t)rowi * OUTLEN); // 512 int4
    const int4* svv = (const int4*)(sub_off  + (size_t)rowi * OUTLEN);
    int* outr = out + (size_t)rowi * OUTLEN;

    int* row32 = (int*)row;
    const int dump = OUTLEN + tid;

    // ---- loads: fully lane-contiguous across the block ----
    const int4 mt = mv[tid];
    const int4 xt = xv[tid];
    const int4 i0 = ivv[2 * tid];
    const int4 i1 = ivv[2 * tid + 1];
    const int4 s0 = svv[2 * tid];
    const int4 s1 = svv[2 * tid + 1];

    const int mm[4] = { mt.x, mt.y, mt.z, mt.w };
    const int xx[4] = { xt.x, xt.y, xt.z, xt.w };
    const int iA[4] = { i0.x, i0.z, i1.x, i1.z }; // even doubled slots
    const int iB[4] = { i0.y, i0.w, i1.y, i1.w }; // odd doubled slots
    const int sO[4] = { s0.x, s0.z, s1.x, s1.z }; // sub_off at even slots

    // ---- per-thread emit count ----
    int cnt = 0;
#pragma unroll
    for (int k = 0; k < 4; ++k)
        cnt += (mm[k] == 0) ? 2 : ((mm[k] == 1) ? 0 : 1);

    // ---- wave scan (6 steps) ----
    int incl = cnt;
#pragma unroll
    for (int d = 1; d < 64; d <<= 1) {
        int t = __shfl_up(incl, d, 64);
        if (lane >= d) incl += t;
    }
    if (lane == 63) wtot[w] = incl;             // wave total
    __syncthreads();

    // ---- block prefix across the 4 waves ----
    int prefix = 0, total = 0;
#pragma unroll
    for (int i = 0; i < 4; ++i) {
        const int t = wtot[i];
        prefix += (i < w) ? t : 0;
        total  += t;
    }
    int p = prefix + incl - cnt;                // exclusive offset in row

    // ---- branch-free emit; dead writes to per-thread dump slot ----
#pragma unroll
    for (int k = 0; k < 4; ++k) {
        const int m_  = mm[k];
        const int cc  = (m_ == 0) ? 2 : ((m_ == 1) ? 0 : 1);
        const int sub = (xx[k] + sO[k] + 1) & 3;
        const int e0  = (m_ == 0) ? iA[k] : ((m_ == 2) ? sub : xx[k]);
        row[(cc != 0) ? p       : dump] = (unsigned char)e0;
        row[(cc == 2) ? (p + 1) : dump] = (unsigned char)iB[k];
        p += cc;
    }

    // ---- pad tail bytes [total, OUTLEN) with PAD_SYM ----
    const int a4 = (total + 3) & ~3;
    if (tid < a4 - total) row[total + tid] = (unsigned char)PAD_SYM;
    for (int j4 = (a4 >> 2) + tid; j4 < (OUTLEN >> 2); j4 += 256)
        row32[j4] = 0x04040404;

    __syncthreads();

    // ---- store: thread reads 2 dwords (8 symbols), widens, 2 NT int4 stores ----
#pragma unroll
    for (int k = 0; k < 2; ++k) {
        const unsigned int d = *(const unsigned int*)(row + k * 1024 + tid * 4);
        iv4 v;
        v.x = (int)(d & 0xffu);
        v.y = (int)((d >> 8)  & 0xffu);
        v.z = (int)((d >> 16) & 0xffu);
        v.w = (int)(d >> 24);
        __builtin_nontemporal_store(v, (iv4*)(outr + k * 1024 + tid * 4));
    }
}

extern "C" void kernel_launch(void* const* d_in, const int* in_sizes, int n_in,
                              void* d_out, int out_size, void* d_ws, size_t ws_size,
                              hipStream_t stream) {
    const int* x        = (const int*)d_in[0];
    const int* mask     = (const int*)d_in[1];
    const int* ins_rand = (const int*)d_in[2];
    const int* sub_off  = (const int*)d_in[3];
    int* out            = (int*)d_out;

    const int B = in_sizes[1] / NPOS;           // mask is [B, N]
    ids_gallager_kernel<<<B, 256, 0, stream>>>(x, mask, ins_rand, sub_off, out, B);
}